// Round 5
// baseline (24.718 us; speedup 1.0000x reference)
//
#include <hip/hip_runtime.h>

// PadMaskedSequence, single fused kernel, ONE WAVE per (batch, chunk-of-16-rows).
// d_out layout: x_ [B*T*D] f32, then lens [B] as float.
//
// 4096 single-wave blocks (16/CU) for fine-grained load balance. Each block:
// (1) packed popcount over the L2-resident mask row -> prefix P (= rows before
// this chunk) and total L (= lens) in one 64-bit shuffle reduction, no LDS,
// no barriers; (2) ballot -> bitmask of selected rows in the chunk; (3) copies
// selected rows to output rows P+i (2-unrolled, nontemporal stores);
// (4) zero-pads output rows [max(j0,L), j0+16). Every output row written
// exactly once; no inter-block communication.

typedef float f32x4 __attribute__((ext_vector_type(4)));

#define BLK 64
#define ROWS 16

__global__ __launch_bounds__(BLK) void pad_masked_fused(
    const float* __restrict__ x,
    const int* __restrict__ mask,
    float* __restrict__ out,
    float* __restrict__ lens_f,
    int T, int D4) {

    const int c = blockIdx.x;
    const int b = blockIdx.y;
    const int lane = threadIdx.x;   // 0..63, one wave
    const int j0 = c * ROWS;

    const int* mrow = mask + (size_t)b * T;

    // ---- packed popcount: pre = sum mask[0:j0), all = sum mask[0:T) ----
    // j0 % 4 == 0 and e % 4 == 0, so an int4 never straddles j0.
    int pre = 0, all = 0;
    for (int e = lane * 4; e < T; e += BLK * 4) {
        const int4 mv = *reinterpret_cast<const int4*>(mrow + e);
        const int s4 = (mv.x != 0) + (mv.y != 0) + (mv.z != 0) + (mv.w != 0);
        all += s4;
        if (e < j0) pre += s4;
    }
    unsigned long long packed = (unsigned long long)(unsigned)pre |
                                ((unsigned long long)(unsigned)all << 32);
    #pragma unroll
    for (int off = 32; off; off >>= 1) packed += __shfl_xor(packed, off);
    const int P = (int)(packed & 0xffffffffull);  // output base row of chunk
    const int L = (int)(packed >> 32);            // lens[b]

    if (c == 0 && lane == 0) lens_f[b] = (float)L;

    // ---- selected rows of this chunk as a wave-uniform bitmask ----
    const int myrow = (lane < ROWS) ? (mrow[j0 + lane] != 0) : 0;
    unsigned long long s = __ballot(myrow);

    const f32x4* xrow = reinterpret_cast<const f32x4*>(x) +
                        ((size_t)b * T + j0) * (size_t)D4;
    f32x4* obase = reinterpret_cast<f32x4*>(out) + (size_t)b * T * (size_t)D4;
    const f32x4 z = {0.f, 0.f, 0.f, 0.f};

    // ---- copy selected rows (2-unrolled for ILP), nontemporal stores ----
    int i = 0;
    while (s) {
        const int r0 = (int)__builtin_ctzll(s); s &= s - 1;
        const bool h2 = (s != 0);
        const int r1 = h2 ? (int)__builtin_ctzll(s) : 0;
        if (h2) s &= s - 1;
        for (int t = lane; t < D4; t += 64) {
            const f32x4 v0 = xrow[(size_t)r0 * D4 + t];
            f32x4 v1 = z;
            if (h2) v1 = xrow[(size_t)r1 * D4 + t];
            __builtin_nontemporal_store(v0, &obase[(size_t)(P + i) * D4 + t]);
            if (h2) __builtin_nontemporal_store(v1, &obase[(size_t)(P + i + 1) * D4 + t]);
        }
        i += h2 ? 2 : 1;
    }

    // ---- zero-pad rows >= L within this chunk's output range ----
    const int zstart = (L > j0) ? L : j0;
    for (int j = zstart; j < j0 + ROWS; ++j)
        for (int t = lane; t < D4; t += 64)
            __builtin_nontemporal_store(z, &obase[(size_t)j * D4 + t]);
}

extern "C" void kernel_launch(void* const* d_in, const int* in_sizes, int n_in,
                              void* d_out, int out_size, void* d_ws, size_t ws_size,
                              hipStream_t stream) {
    const float* x = (const float*)d_in[0];
    const int* mask = (const int*)d_in[1];

    const int Nx = in_sizes[0];   // B*T*D
    const int BT = in_sizes[1];   // B*T
    const int B = out_size - Nx;  // lens appended after x_
    const int T = BT / B;
    const int D = Nx / BT;
    const int D4 = D / 4;

    float* out = (float*)d_out;
    float* lens_f = out + (size_t)Nx;

    dim3 grid(T / ROWS, B);
    pad_masked_fused<<<grid, BLK, 0, stream>>>(x, mask, out, lens_f, T, D4);
}